// Round 15
// baseline (472.528 us; speedup 1.0000x reference)
//
#include <hip/hip_runtime.h>
#include <hip/hip_cooperative_groups.h>
#include <stdint.h>

#define NB 4
#define NC 256
#define NCI 128
#define NN 4096

typedef __attribute__((ext_vector_type(8))) short short8;
typedef __attribute__((ext_vector_type(4))) float f32x4;

__device__ __forceinline__ float bf2f(unsigned short u) {
    union { unsigned int i; float f; } v; v.i = ((unsigned int)u) << 16; return v.f;
}
__device__ __forceinline__ unsigned short f2bf(float f) {
    union { unsigned int i; float f; } v; v.f = f;
    unsigned int b = v.i;
    b += 0x7FFFu + ((b >> 16) & 1u);   // RNE
    return (unsigned short)(b >> 16);
}

// ---------------------------------------------------------------- sentinel fill
__global__ void k_fill(float* __restrict__ p, float v, int n) {
    int i = blockIdx.x * blockDim.x + threadIdx.x;
    if (i < n) p[i] = v;
}

// ---------------------------------------------------------------- fused kernel
// ONE cooperative launch replaces k_split + k_qkv2 + k_attn (the non-k_attn
// pool was a constant ~81 us across all rounds = 2 extra launches + gaps +
// k_qkv2; fusing removes the fixed costs). 256 blocks x 1024 threads,
// 148 KB LDS -> exactly 1 block/CU -> co-residency for grid.sync().
//   Phase A: weight split/convert (1 elem/thread, 131072 elems)
//   Phase B: phi (hi/lo) + g projections; block = one 64-wide n-tile
//            (16 waves = 8 ci-groups x 2 n-halves, c0-step 128)
//   Phase C: R9 attention body VERBATIM (best measured: 108 us, no spill)
__global__ __launch_bounds__(1024, 4) void k_fused(
    const float* __restrict__ x,
    const float* __restrict__ tw, const float* __restrict__ tb,
    const float* __restrict__ pw, const float* __restrict__ pb,
    const float* __restrict__ gw, const float* __restrict__ gb,
    const float* __restrict__ ow, const float* __restrict__ obias,
    unsigned short* __restrict__ ws16, float* __restrict__ y) {
    const float LOG2E = 1.4426950408889634f;
    namespace cg = cooperative_groups;
    cg::grid_group grid = cg::this_grid();

    unsigned short* phiH = ws16;                 // [B][N][Ci] bf16 hi
    unsigned short* phiL = ws16 + 2097152;       // [B][N][Ci] bf16 lo
    unsigned short* gmat = ws16 + 4194304;       // [B][Ci][N] bf16
    unsigned short* wbuf = ws16 + 6291456;       // WtH,WtL,WpH,WpL,WgH,WoH
    const unsigned short* WtH = wbuf;
    const unsigned short* WtL = wbuf + 32768;
    const unsigned short* WpH = wbuf + 65536;
    const unsigned short* WpL = wbuf + 98304;
    const unsigned short* WgH = wbuf + 131072;
    const unsigned short* WoH = wbuf + 163840;

    __shared__ __align__(16) char smem[148480];

    const int id = blockIdx.x;
    const int tid = threadIdx.x, lane = tid & 63, wave = tid >> 6;  // wave 0..15
    const int col = lane & 15, quad = lane >> 4;

    // ================= phase A: weight split/convert =================
    {
        int gid = id * 1024 + tid;
        if (gid < 131072) {
            int m = gid >> 15, i = gid & 32767;
            if (m == 0) {
                float v = tw[i] * LOG2E;
                unsigned short h = f2bf(v);
                wbuf[i] = h;
                wbuf[32768 + i] = f2bf(v - bf2f(h));
            } else if (m == 1) {
                float v = pw[i];
                unsigned short h = f2bf(v);
                wbuf[65536 + i] = h;
                wbuf[98304 + i] = f2bf(v - bf2f(h));
            } else if (m == 2) {
                wbuf[131072 + i] = f2bf(gw[i]);
            } else {
                wbuf[163840 + i] = f2bf(ow[i]);
            }
        }
    }
    __threadfence();
    grid.sync();

    // ================= phase B: phi (hi/lo) + g projections =================
    // block -> (b2, 64-wide n-tile); wave -> (ci-group of 16, n-half of 32)
    {
        unsigned short* sXh = (unsigned short*)(smem);           // [64 n][136]
        unsigned short* sXl = (unsigned short*)(smem + 17408);
        const int b2 = id >> 6, n0b = (id & 63) * 64;
        const int cig = wave >> 1, nh = wave & 1;
        const int wm16 = cig * 16;

        f32x4 accP[2], accG[2];
#pragma unroll
        for (int j = 0; j < 2; j++)
#pragma unroll
            for (int e = 0; e < 4; e++) { accP[j][e] = 0.f; accG[j][e] = 0.f; }

        for (int c0 = 0; c0 < NC; c0 += 128) {
            if (c0) __syncthreads();            // prev sX reads done
            {   // stage x transpose+split: 64 n x 128 c, 1024 threads
                int cp = tid >> 4, n4 = (tid & 15) * 4;
                const float* xp = x + ((size_t)(b2 * NC + c0 + 2 * cp)) * NN + n0b + n4;
                float4 a = *(const float4*)xp;
                float4 c = *(const float4*)(xp + NN);
                float av[4] = { a.x, a.y, a.z, a.w };
                float cv[4] = { c.x, c.y, c.z, c.w };
#pragma unroll
                for (int j = 0; j < 4; j++) {
                    unsigned short ha = f2bf(av[j]), hc = f2bf(cv[j]);
                    unsigned short la = f2bf(av[j] - bf2f(ha)), lc = f2bf(cv[j] - bf2f(hc));
                    *(unsigned int*)&sXh[(n4 + j) * 136 + 2 * cp] =
                        (unsigned int)ha | ((unsigned int)hc << 16);
                    *(unsigned int*)&sXl[(n4 + j) * 136 + 2 * cp] =
                        (unsigned int)la | ((unsigned int)lc << 16);
                }
            }
            __syncthreads();
            short8 ah[4], al[4], ag[4];
#pragma unroll
            for (int ks = 0; ks < 4; ks++) {
                size_t w = (size_t)(wm16 + col) * NC + c0 + ks * 32 + quad * 8;
                ah[ks] = *(const short8*)&WpH[w];
                al[ks] = *(const short8*)&WpL[w];
                ag[ks] = *(const short8*)&WgH[w];
            }
#pragma unroll
            for (int ks = 0; ks < 4; ks++)
#pragma unroll
                for (int j = 0; j < 2; j++) {
                    int nrow = nh * 32 + j * 16 + col;
                    short8 bh = *(const short8*)&sXh[nrow * 136 + ks * 32 + quad * 8];
                    short8 bl = *(const short8*)&sXl[nrow * 136 + ks * 32 + quad * 8];
                    accP[j] = __builtin_amdgcn_mfma_f32_16x16x32_bf16(ah[ks], bh, accP[j], 0, 0, 0);
                    accP[j] = __builtin_amdgcn_mfma_f32_16x16x32_bf16(ah[ks], bl, accP[j], 0, 0, 0);
                    accP[j] = __builtin_amdgcn_mfma_f32_16x16x32_bf16(al[ks], bh, accP[j], 0, 0, 0);
                    accG[j] = __builtin_amdgcn_mfma_f32_16x16x32_bf16(ag[ks], bh, accG[j], 0, 0, 0);
                }
        }
        {
            int mrow = wm16 + quad * 4;
#pragma unroll
            for (int j = 0; j < 2; j++) {
                int n = n0b + nh * 32 + j * 16 + col;
                unsigned short h[4], l[4];
#pragma unroll
                for (int e = 0; e < 4; e++) {
                    float v = accP[j][e] + pb[mrow + e];
                    h[e] = f2bf(v);
                    l[e] = f2bf(v - bf2f(h[e]));
                }
                uint2 hv, lv;
                hv.x = (unsigned int)h[0] | ((unsigned int)h[1] << 16);
                hv.y = (unsigned int)h[2] | ((unsigned int)h[3] << 16);
                lv.x = (unsigned int)l[0] | ((unsigned int)l[1] << 16);
                lv.y = (unsigned int)l[2] | ((unsigned int)l[3] << 16);
                *(uint2*)&phiH[((size_t)(b2 * NN + n)) * NCI + mrow] = hv;
                *(uint2*)&phiL[((size_t)(b2 * NN + n)) * NCI + mrow] = lv;
#pragma unroll
                for (int r = 0; r < 4; r++)
                    gmat[((size_t)(b2 * NCI + mrow + r)) * NN + n] =
                        f2bf(accG[j][r] + gb[mrow + r]);
            }
        }
    }
    __threadfence();
    grid.sync();

    // ================= phase C: attention (R9 body verbatim) =================
    // main-loop regions
    unsigned short* sPhiH0 = (unsigned short*)(smem);            // [64 m][128] swz
    unsigned short* sPhiH1 = (unsigned short*)(smem + 16384);
    unsigned short* sPhiL0 = (unsigned short*)(smem + 32768);
    unsigned short* sPhiL1 = (unsigned short*)(smem + 49152);
    unsigned short* sGbase = (unsigned short*)(smem + 65536);    // 4 x [128 c][64] swz
    unsigned short* sPall0 = (unsigned short*)(smem + 131072);   // [64 q][64] swz
    unsigned short* sPall1 = (unsigned short*)(smem + 139264);
    float* sLi             = (float*)(smem + 147456);            // [16 waves][16 q]
    // prologue overlays
    unsigned short* sThH  = (unsigned short*)(smem);             // [64 q][128] swz
    unsigned short* sThL  = (unsigned short*)(smem + 16384);
    unsigned short* sXhA  = (unsigned short*)(smem + 32768);     // [64 n][72] linear
    unsigned short* sXlA  = (unsigned short*)(smem + 41984);
    unsigned short* sXhB  = (unsigned short*)(smem + 51200);
    unsigned short* sXlB  = (unsigned short*)(smem + 60416);
    float* sThF           = (float*)(smem + 32768);              // [64 q][128] f32 swz
    // epilogue overlay
    unsigned short* sO    = (unsigned short*)(smem);             // [64 q][128] swz

    const int xcd = id & 7, slot = id >> 3;                      // slot 0..31
    const int b = xcd >> 1;                                      // batch pinned to 2 XCDs
    const int n0 = (slot * 2 + (xcd & 1)) * 64;
    const int qg = wave >> 2, kh = wave & 3;

    // staged-tile registers (single set; STORET precedes LOADT in each window)
    uint4 rPh, rPl, rG;
    auto LOADT = [&](int m0) {
        int row = tid >> 4, seg = tid & 15;
        size_t src = ((size_t)(b * NN + m0 + row)) * NCI + seg * 8;
        rPh = *(const uint4*)&phiH[src];
        rPl = *(const uint4*)&phiL[src];
        int row2 = tid >> 3, seg2 = tid & 7;
        rG = *(const uint4*)&gmat[((size_t)(b * NCI + row2)) * NN + m0 + seg2 * 8];
    };
    auto STORET = [&](unsigned short* dPh, unsigned short* dPl, unsigned short* dG) {
        int row = tid >> 4, seg = tid & 15;
        int dst = row * 128 + ((seg * 8) ^ ((row & 7) << 3));
        *(uint4*)&dPh[dst] = rPh;
        *(uint4*)&dPl[dst] = rPl;
        int row2 = tid >> 3, seg2 = tid & 7;
        *(uint4*)&dG[row2 * 64 + ((seg2 * 8) ^ ((row2 & 7) << 3))] = rG;
    };

    // ---------------- prologue: theta (log2e-scaled), C-range split across halves
    const int half = wave >> 3;                 // 0: c0 in {0,64}; 1: {128,192}
    const int wci8 = (wave & 7) * 16;           // ci rows covered by this wave
    f32x4 th[4];
#pragma unroll
    for (int j = 0; j < 4; j++)
#pragma unroll
        for (int e = 0; e < 4; e++) th[j][e] = 0.f;

    __syncthreads();                            // phase-B LDS reads done
    for (int s = 0; s < 2; s++) {
        {   // each 512-thread half stages its own c0 chunk of x (transpose+split)
            int set = tid >> 9;                 // == wave>>3
            int t = tid & 511;
            int cp = t >> 4, n4 = (t & 15) * 4;
            int myc0 = set * 128 + s * 64;
            unsigned short* dXh = set ? sXhB : sXhA;
            unsigned short* dXl = set ? sXlB : sXlA;
            const float* xp = x + ((size_t)(b * NC + myc0 + 2 * cp)) * NN + n0 + n4;
            float4 a = *(const float4*)xp;
            float4 c = *(const float4*)(xp + NN);
            float av[4] = { a.x, a.y, a.z, a.w };
            float cv4[4] = { c.x, c.y, c.z, c.w };
#pragma unroll
            for (int j = 0; j < 4; j++) {
                unsigned short ha = f2bf(av[j]), hc = f2bf(cv4[j]);
                unsigned short la = f2bf(av[j] - bf2f(ha)), lc = f2bf(cv4[j] - bf2f(hc));
                *(unsigned int*)&dXh[(n4 + j) * 72 + 2 * cp] =
                    (unsigned int)ha | ((unsigned int)hc << 16);
                *(unsigned int*)&dXl[(n4 + j) * 72 + 2 * cp] =
                    (unsigned int)la | ((unsigned int)lc << 16);
            }
        }
        __syncthreads();
        {
            int c0 = half * 128 + s * 64;
            const unsigned short* mXh = half ? sXhB : sXhA;
            const unsigned short* mXl = half ? sXlB : sXlA;
#pragma unroll
            for (int ks = 0; ks < 2; ks++) {
                size_t w = (size_t)(wci8 + col) * NC + c0 + ks * 32 + quad * 8;
                short8 ah = *(const short8*)&WtH[w];
                short8 al = *(const short8*)&WtL[w];
#pragma unroll
                for (int j = 0; j < 4; j++) {
                    short8 bh = *(const short8*)&mXh[(j * 16 + col) * 72 + ks * 32 + quad * 8];
                    short8 bl = *(const short8*)&mXl[(j * 16 + col) * 72 + ks * 32 + quad * 8];
                    th[j] = __builtin_amdgcn_mfma_f32_16x16x32_bf16(ah, bh, th[j], 0, 0, 0);
                    th[j] = __builtin_amdgcn_mfma_f32_16x16x32_bf16(ah, bl, th[j], 0, 0, 0);
                    th[j] = __builtin_amdgcn_mfma_f32_16x16x32_bf16(al, bh, th[j], 0, 0, 0);
                }
            }
        }
        __syncthreads();
    }
    // merge halves: half 0 writes f32 partials; half 1 adds, biases, splits hi/lo
    if (half == 0) {
#pragma unroll
        for (int j = 0; j < 4; j++) {
            int q = j * 16 + col;
            int ci = (wci8 + quad * 4) ^ ((q & 7) << 2);
            *(f32x4*)&sThF[q * 128 + ci] = th[j];
        }
    }
    __syncthreads();
    if (half == 1) {
#pragma unroll
        for (int j = 0; j < 4; j++) {
            int q = j * 16 + col;
            int cif = (wci8 + quad * 4) ^ ((q & 7) << 2);
            f32x4 o = *(const f32x4*)&sThF[q * 128 + cif];
            unsigned short h[4], l[4];
#pragma unroll
            for (int e = 0; e < 4; e++) {
                float v = o[e] + th[j][e] + tb[wci8 + quad * 4 + e] * LOG2E;
                h[e] = f2bf(v);
                l[e] = f2bf(v - bf2f(h[e]));
            }
            int cisw = (wci8 + quad * 4) ^ ((q & 7) << 3);
            uint2 hv, lv;
            hv.x = (unsigned int)h[0] | ((unsigned int)h[1] << 16);
            hv.y = (unsigned int)h[2] | ((unsigned int)h[3] << 16);
            lv.x = (unsigned int)l[0] | ((unsigned int)l[1] << 16);
            lv.y = (unsigned int)l[2] | ((unsigned int)l[3] << 16);
            *(uint2*)&sThH[q * 128 + cisw] = hv;
            *(uint2*)&sThL[q * 128 + cisw] = lv;
        }
    }
    __syncthreads();
    // theta fragments for this wave's 16-query group, held for the whole kernel
    short8 qh[4], ql[4];
    {
        int qrow = qg * 16 + col;
        int qsw = (qrow & 7) << 3;
#pragma unroll
        for (int ks = 0; ks < 4; ks++) {
            int off = (ks * 32 + quad * 8) ^ qsw;
            qh[ks] = *(const short8*)&sThH[qrow * 128 + off];
            ql[ks] = *(const short8*)&sThL[qrow * 128 + off];
        }
    }
    // prestage: tile 0 -> phi[0]/G[0]; tile 1 staged into registers
    LOADT(0);
    __syncthreads();                 // all waves finished reading sThH/sThL
    STORET(sPhiH0, sPhiL0, sGbase);  // tile 0 -> phi0, G slot 0
    LOADT(64);                       // tile 1 -> regs
    __syncthreads();                 // phi0/G0 visible

    // ---------------- main K-loop: 1 barrier/tile, 2-step unroll, static phi/P
    f32x4 oacc[2];
#pragma unroll
    for (int i = 0; i < 2; i++)
#pragma unroll
        for (int e = 0; e < 4; e++) oacc[i][e] = 0.f;
    float li[4] = { 0.f, 0.f, 0.f, 0.f };      // per-lane partial (this col's keys)

    auto step = [&](const unsigned short* cPhiH, const unsigned short* cPhiL,
                    unsigned short* nPhiH, unsigned short* nPhiL,
                    unsigned short* wG, const unsigned short* rGb,
                    unsigned short* wPall, const unsigned short* rPall,
                    int m_next, bool do_pv) {
        STORET(nPhiH, nPhiL, wG);
        LOADT(m_next);

        // QK(t): 16 queries (regs) x this wave's 16-key quarter
        f32x4 S;
#pragma unroll
        for (int e = 0; e < 4; e++) S[e] = 0.f;
        {
            int kcol = kh * 16 + col;
            int kswz = (kcol & 7) << 3;
#pragma unroll
            for (int ks = 0; ks < 4; ks++) {
                int off = (ks * 32 + quad * 8) ^ kswz;
                short8 ph = *(const short8*)&cPhiH[kcol * 128 + off];
                short8 pl = *(const short8*)&cPhiL[kcol * 128 + off];
                S = __builtin_amdgcn_mfma_f32_16x16x32_bf16(qh[ks], ph, S, 0, 0, 0);
                S = __builtin_amdgcn_mfma_f32_16x16x32_bf16(qh[ks], pl, S, 0, 0, 0);
                S = __builtin_amdgcn_mfma_f32_16x16x32_bf16(ql[ks], ph, S, 0, 0, 0);
            }
        }
        // PV(t-1): independent MFMAs fill the QK->exp2 dependency shadow
        if (do_pv) {
            short8 pf[2], af[2][2];
            int qrow = qg * 16 + col;
            int qsw = (qrow & 7) << 3;
#pragma unroll
            for (int ks = 0; ks < 2; ks++)
                pf[ks] = *(const short8*)&rPall[qrow * 64 + ((ks * 32 + quad * 8) ^ qsw)];
#pragma unroll
            for (int ct = 0; ct < 2; ct++) {
                int grow = kh * 32 + ct * 16 + col;
                int gsw = (grow & 7) << 3;
#pragma unroll
                for (int ks = 0; ks < 2; ks++)
                    af[ct][ks] = *(const short8*)&rGb[grow * 64 + ((ks * 32 + quad * 8) ^ gsw)];
            }
#pragma unroll
            for (int ct = 0; ct < 2; ct++)
#pragma unroll
                for (int ks = 0; ks < 2; ks++)
                    oacc[ct] = __builtin_amdgcn_mfma_f32_16x16x32_bf16(
                        af[ct][ks], pf[ks], oacc[ct], 0, 0, 0);
        }
        // softmax(t): per-lane li accumulation, P write swizzled
#pragma unroll
        for (int r = 0; r < 4; r++) {
            float p = exp2f(S[r]);
            li[r] += p;
            int q = qg * 16 + quad * 4 + r;
            wPall[q * 64 + ((kh * 16 + col) ^ ((q & 7) << 3))] = f2bf(p);
        }
        __syncthreads();             // single barrier per tile
    };

    // G slot offsets in shorts (slot k = k*8192). Step A = even t, B = odd t.
    int gwA = 8192, grA = 24576, gwB = 16384, grB = 0;
    for (int it = 0; it < 32; ++it) {
        int mA = it * 128 + 128; if (mA > 4032) mA = 4032;   // tile t+2 (clamped tail)
        int mB = it * 128 + 192; if (mB > 4032) mB = 4032;
        step(sPhiH0, sPhiL0, sPhiH1, sPhiL1, sGbase + gwA, sGbase + grA,
             sPall0, sPall1, mA, it != 0);
        step(sPhiH1, sPhiL1, sPhiH0, sPhiL0, sGbase + gwB, sGbase + grB,
             sPall1, sPall0, mB, true);
        gwA ^= 16384; grA ^= 16384; gwB ^= 16384; grB ^= 16384;
    }
    // final PV(63): P in pall[1], G in slot 63%4 = 3 (static)
    {
        short8 pf[2], af[2][2];
        int qrow = qg * 16 + col;
        int qsw = (qrow & 7) << 3;
#pragma unroll
        for (int ks = 0; ks < 2; ks++)
            pf[ks] = *(const short8*)&sPall1[qrow * 64 + ((ks * 32 + quad * 8) ^ qsw)];
#pragma unroll
        for (int ct = 0; ct < 2; ct++) {
            int grow = kh * 32 + ct * 16 + col;
            int gsw = (grow & 7) << 3;
#pragma unroll
            for (int ks = 0; ks < 2; ks++)
                af[ct][ks] = *(const short8*)&sGbase[24576 + grow * 64 + ((ks * 32 + quad * 8) ^ gsw)];
        }
#pragma unroll
        for (int ct = 0; ct < 2; ct++)
#pragma unroll
            for (int ks = 0; ks < 2; ks++)
                oacc[ct] = __builtin_amdgcn_mfma_f32_16x16x32_bf16(
                    af[ct][ks], pf[ks], oacc[ct], 0, 0, 0);
    }

    // ---------------- li: one wave-level reduce over the 16 cols, then merge kh
#pragma unroll
    for (int r = 0; r < 4; r++) {
        float rs = li[r];
#pragma unroll
        for (int off = 1; off < 16; off <<= 1) rs += __shfl_xor(rs, off);
        li[r] = rs;
    }
    if (col == 0) {
#pragma unroll
        for (int r = 0; r < 4; r++) sLi[wave * 16 + quad * 4 + r] = li[r];
    }
    __syncthreads();
    float inv = 1.0f / (sLi[(qg * 4 + 0) * 16 + col] + sLi[(qg * 4 + 1) * 16 + col] +
                        sLi[(qg * 4 + 2) * 16 + col] + sLi[(qg * 4 + 3) * 16 + col]);

    // O -> LDS (bf16, swizzled), overlays dead phi0
#pragma unroll
    for (int ct = 0; ct < 2; ct++) {
        int q = qg * 16 + col;
        int ci = kh * 32 + ct * 16 + quad * 4;
        int cisw = ci ^ ((q & 7) << 3);
        uint2 v;
        unsigned short p0 = f2bf(oacc[ct][0] * inv);
        unsigned short p1 = f2bf(oacc[ct][1] * inv);
        unsigned short p2 = f2bf(oacc[ct][2] * inv);
        unsigned short p3 = f2bf(oacc[ct][3] * inv);
        v.x = (unsigned int)p0 | ((unsigned int)p1 << 16);
        v.y = (unsigned int)p2 | ((unsigned int)p3 << 16);
        *(uint2*)&sO[q * 128 + cisw] = v;
    }
    __syncthreads();
    // out-proj: wave's 16-o tile + bias + residual; Wo A-frags straight from global
    f32x4 acc[4];
#pragma unroll
    for (int j = 0; j < 4; j++)
#pragma unroll
        for (int e = 0; e < 4; e++) acc[j][e] = 0.f;
#pragma unroll
    for (int ks = 0; ks < 4; ks++) {
        short8 af2 = *(const short8*)&WoH[(size_t)(wave * 16 + col) * NCI + ks * 32 + quad * 8];
#pragma unroll
        for (int j = 0; j < 4; j++) {
            int row = j * 16 + col;
            short8 bf = *(const short8*)&sO[row * 128 + ((ks * 32 + quad * 8) ^ ((row & 7) << 3))];
            acc[j] = __builtin_amdgcn_mfma_f32_16x16x32_bf16(af2, bf, acc[j], 0, 0, 0);
        }
    }
#pragma unroll
    for (int j = 0; j < 4; j++)
#pragma unroll
        for (int e = 0; e < 4; e++) {
            int o = wave * 16 + quad * 4 + e;
            size_t idx = ((size_t)(b * NC + o)) * NN + n0 + j * 16 + col;
            y[idx] = acc[j][e] + obias[o] + x[idx];
        }
}

// ---------------------------------------------------------------- launch
extern "C" void kernel_launch(void* const* d_in, const int* in_sizes, int n_in,
                              void* d_out, int out_size, void* d_ws, size_t ws_size,
                              hipStream_t stream) {
    float* y = (float*)d_out;

    bool sizes_ok = (n_in == 9) &&
        in_sizes[0] == NB * NC * NN && in_sizes[1] == NCI * NC && in_sizes[2] == NCI &&
        in_sizes[3] == NCI * NC && in_sizes[4] == NCI && in_sizes[5] == NCI * NC &&
        in_sizes[6] == NCI && in_sizes[7] == NC * NCI && in_sizes[8] == NC &&
        out_size == NB * NC * NN;
    if (!sizes_ok) {
        k_fill<<<(out_size + 255) / 256, 256, 0, stream>>>(y, 777.0f, out_size);
        return;
    }
    if (ws_size < (size_t)16 * 1024 * 1024) {
        k_fill<<<(out_size + 255) / 256, 256, 0, stream>>>(y, 555.0f, out_size);
        return;
    }

    const float* x  = (const float*)d_in[0];
    const float* tw = (const float*)d_in[1];
    const float* tb = (const float*)d_in[2];
    const float* pw = (const float*)d_in[3];
    const float* pb = (const float*)d_in[4];
    const float* gw = (const float*)d_in[5];
    const float* gb = (const float*)d_in[6];
    const float* ow = (const float*)d_in[7];
    const float* obias = (const float*)d_in[8];
    unsigned short* ws16 = (unsigned short*)d_ws;

    void* args[] = { (void*)&x, (void*)&tw, (void*)&tb, (void*)&pw, (void*)&pb,
                     (void*)&gw, (void*)&gb, (void*)&ow, (void*)&obias,
                     (void*)&ws16, (void*)&y };
    hipLaunchCooperativeKernel((void*)k_fused, dim3(256), dim3(1024), args, 0, stream);
}

// Round 16
// 188.994 us; speedup vs baseline: 2.5002x; 2.5002x over previous
//
#include <hip/hip_runtime.h>
#include <stdint.h>

#define NB 4
#define NC 256
#define NCI 128
#define NN 4096

typedef __attribute__((ext_vector_type(8))) short short8;
typedef __attribute__((ext_vector_type(4))) float f32x4;

__device__ __forceinline__ float bf2f(unsigned short u) {
    union { unsigned int i; float f; } v; v.i = ((unsigned int)u) << 16; return v.f;
}
__device__ __forceinline__ unsigned short f2bf(float f) {
    union { unsigned int i; float f; } v; v.f = f;
    unsigned int b = v.i;
    b += 0x7FFFu + ((b >> 16) & 1u);   // RNE
    return (unsigned short)(b >> 16);
}

// ---------------------------------------------------------------- sentinel fill
__global__ void k_fill(float* __restrict__ p, float v, int n) {
    int i = blockIdx.x * blockDim.x + threadIdx.x;
    if (i < n) p[i] = v;
}

// ---------------------------------------------------------------- K0: weight split/convert
__global__ __launch_bounds__(256) void k_split(
    const float* __restrict__ Wt, const float* __restrict__ Wp,
    const float* __restrict__ Wg, const float* __restrict__ Wo,
    unsigned short* __restrict__ wbuf) {
    const float LOG2E = 1.4426950408889634f;
    int m = blockIdx.y;
    int i = blockIdx.x * 256 + threadIdx.x;
    if (m == 0) {
        float v = Wt[i] * LOG2E;
        unsigned short h = f2bf(v);
        wbuf[i] = h;
        wbuf[32768 + i] = f2bf(v - bf2f(h));
    } else if (m == 1) {
        float v = Wp[i];
        unsigned short h = f2bf(v);
        wbuf[65536 + i] = h;
        wbuf[98304 + i] = f2bf(v - bf2f(h));
    } else if (m == 2) {
        wbuf[131072 + i] = f2bf(Wg[i]);
    } else {
        wbuf[163840 + i] = f2bf(Wo[i]);
    }
}

// ---------------------------------------------------------------- K1: phi (hi/lo) + g projections
__global__ __launch_bounds__(256, 2) void k_qkv2(
    const float* __restrict__ x,
    const unsigned short* __restrict__ WpH, const unsigned short* __restrict__ WpL,
    const unsigned short* __restrict__ WgH,
    const float* __restrict__ bp, const float* __restrict__ bg,
    unsigned short* __restrict__ phiH, unsigned short* __restrict__ phiL,
    unsigned short* __restrict__ gout) {
    __shared__ __align__(16) unsigned short sXh[32 * 72];
    __shared__ __align__(16) unsigned short sXl[32 * 72];
    const int b = blockIdx.y, n0 = blockIdx.x * 32;
    const int tid = threadIdx.x, lane = tid & 63, wave = tid >> 6;
    const int col = lane & 15, quad = lane >> 4;
    const int wm = wave * 32;

    f32x4 accP[2][2], accG[2][2];
#pragma unroll
    for (int i = 0; i < 2; i++)
#pragma unroll
        for (int j = 0; j < 2; j++)
#pragma unroll
            for (int e = 0; e < 4; e++) { accP[i][j][e] = 0.f; accG[i][j][e] = 0.f; }

    for (int c0 = 0; c0 < NC; c0 += 64) {
        __syncthreads();
        short8 ah[2][2], al[2][2], ag[2][2];
#pragma unroll
        for (int ks = 0; ks < 2; ks++)
#pragma unroll
            for (int i = 0; i < 2; i++) {
                size_t w = (size_t)(wm + i * 16 + col) * NC + c0 + ks * 32 + quad * 8;
                ah[ks][i] = *(const short8*)&WpH[w];
                al[ks][i] = *(const short8*)&WpL[w];
                ag[ks][i] = *(const short8*)&WgH[w];
            }
        {
            int cp = tid >> 3, n4 = (tid & 7) * 4;
            const float* xp = x + ((size_t)(b * NC + c0 + 2 * cp)) * NN + n0 + n4;
            float4 a = *(const float4*)xp;
            float4 c = *(const float4*)(xp + NN);
            float av[4] = { a.x, a.y, a.z, a.w };
            float cv[4] = { c.x, c.y, c.z, c.w };
#pragma unroll
            for (int j = 0; j < 4; j++) {
                unsigned short ha = f2bf(av[j]), hc = f2bf(cv[j]);
                unsigned short la = f2bf(av[j] - bf2f(ha)), lc = f2bf(cv[j] - bf2f(hc));
                *(unsigned int*)&sXh[(n4 + j) * 72 + 2 * cp] =
                    (unsigned int)ha | ((unsigned int)hc << 16);
                *(unsigned int*)&sXl[(n4 + j) * 72 + 2 * cp] =
                    (unsigned int)la | ((unsigned int)lc << 16);
            }
        }
        __syncthreads();
#pragma unroll
        for (int ks = 0; ks < 2; ks++)
#pragma unroll
            for (int j = 0; j < 2; j++) {
                short8 bh = *(const short8*)&sXh[(j * 16 + col) * 72 + ks * 32 + quad * 8];
                short8 bl = *(const short8*)&sXl[(j * 16 + col) * 72 + ks * 32 + quad * 8];
#pragma unroll
                for (int i = 0; i < 2; i++) {
                    accP[i][j] = __builtin_amdgcn_mfma_f32_16x16x32_bf16(ah[ks][i], bh, accP[i][j], 0, 0, 0);
                    accP[i][j] = __builtin_amdgcn_mfma_f32_16x16x32_bf16(ah[ks][i], bl, accP[i][j], 0, 0, 0);
                    accP[i][j] = __builtin_amdgcn_mfma_f32_16x16x32_bf16(al[ks][i], bh, accP[i][j], 0, 0, 0);
                    accG[i][j] = __builtin_amdgcn_mfma_f32_16x16x32_bf16(ag[ks][i], bh, accG[i][j], 0, 0, 0);
                }
            }
    }
#pragma unroll
    for (int i = 0; i < 2; i++) {
        int mrow = wm + i * 16 + quad * 4;
#pragma unroll
        for (int j = 0; j < 2; j++) {
            int n = n0 + j * 16 + col;
            unsigned short h[4], l[4];
#pragma unroll
            for (int e = 0; e < 4; e++) {
                float v = accP[i][j][e] + bp[mrow + e];
                h[e] = f2bf(v);
                l[e] = f2bf(v - bf2f(h[e]));
            }
            uint2 hv, lv;
            hv.x = (unsigned int)h[0] | ((unsigned int)h[1] << 16);
            hv.y = (unsigned int)h[2] | ((unsigned int)h[3] << 16);
            lv.x = (unsigned int)l[0] | ((unsigned int)l[1] << 16);
            lv.y = (unsigned int)l[2] | ((unsigned int)l[3] << 16);
            *(uint2*)&phiH[((size_t)(b * NN + n)) * NCI + mrow] = hv;
            *(uint2*)&phiL[((size_t)(b * NN + n)) * NCI + mrow] = lv;
#pragma unroll
            for (int r = 0; r < 4; r++)
                gout[((size_t)(b * NCI + mrow + r)) * NN + n] = f2bf(accG[i][j][r] + bg[mrow + r]);
        }
    }
}

// ---------------------------------------------------------------- K2: fused attention, 16 waves
// R9 configuration — the session's best measured state (total 189.7 us,
// k_attn 108.2 us, VGPR 64, no scratch). Locked in after rounds 10-15
// falsified: QK-redundancy halving (x3, VGPR-budget-bound), QK chain split
// (-7%), cooperative-fusion (grid.sync ~125 us/sync on 8-XCD MI355X).
// Block: batch b, 64 queries, 256 blocks = 1/CU, 1024 threads = 4 waves/SIMD.
// Window t: STORET(t+1) [regs a full window old], LOADT(t+2) [clamped tail],
// QK(t) [phi t&1], PV(t-1) [P (t-1)&1, G (t-1)%4], softmax+Pwrite(t) [P t&1],
// one __syncthreads(). G ring 4-deep so the schedule has period 2 -> 2-step
// unrolled loop with static phi/P pointers; G slots are scalar XOR offsets.
__global__ __launch_bounds__(1024, 4) void k_attn(
    const float* __restrict__ x,
    const unsigned short* __restrict__ WtH, const unsigned short* __restrict__ WtL,
    const float* __restrict__ bt,
    const unsigned short* __restrict__ phiH, const unsigned short* __restrict__ phiL,
    const unsigned short* __restrict__ gmat,
    const unsigned short* __restrict__ WoH, const float* __restrict__ bo,
    float* __restrict__ y) {
    const float LOG2E = 1.4426950408889634f;
    __shared__ __align__(16) char smem[148480];
    // main-loop regions
    unsigned short* sPhiH0 = (unsigned short*)(smem);            // [64 m][128] swz
    unsigned short* sPhiH1 = (unsigned short*)(smem + 16384);
    unsigned short* sPhiL0 = (unsigned short*)(smem + 32768);
    unsigned short* sPhiL1 = (unsigned short*)(smem + 49152);
    unsigned short* sGbase = (unsigned short*)(smem + 65536);    // 4 x [128 c][64] swz
    unsigned short* sPall0 = (unsigned short*)(smem + 131072);   // [64 q][64] swz
    unsigned short* sPall1 = (unsigned short*)(smem + 139264);
    float* sLi             = (float*)(smem + 147456);            // [16 waves][16 q]
    // prologue overlays (all dead before first main-loop store)
    unsigned short* sThH  = (unsigned short*)(smem);             // [64 q][128] swz
    unsigned short* sThL  = (unsigned short*)(smem + 16384);
    unsigned short* sXhA  = (unsigned short*)(smem + 32768);     // [64 n][72] linear
    unsigned short* sXlA  = (unsigned short*)(smem + 41984);
    unsigned short* sXhB  = (unsigned short*)(smem + 51200);
    unsigned short* sXlB  = (unsigned short*)(smem + 60416);
    float* sThF           = (float*)(smem + 32768);              // [64 q][128] f32 swz (after sX dead)
    // epilogue overlay
    unsigned short* sO    = (unsigned short*)(smem);             // [64 q][128] swz

    const int id = blockIdx.x;
    const int xcd = id & 7, slot = id >> 3;                      // slot 0..31
    const int b = xcd >> 1;                                      // batch pinned to 2 XCDs
    const int n0 = (slot * 2 + (xcd & 1)) * 64;

    const int tid = threadIdx.x, lane = tid & 63, wave = tid >> 6;  // wave 0..15
    const int col = lane & 15, quad = lane >> 4;
    const int qg = wave >> 2, kh = wave & 3;

    // staged-tile registers (single set; STORET precedes LOADT in each window)
    uint4 rPh, rPl, rG;
    auto LOADT = [&](int m0) {
        int row = tid >> 4, seg = tid & 15;
        size_t src = ((size_t)(b * NN + m0 + row)) * NCI + seg * 8;
        rPh = *(const uint4*)&phiH[src];
        rPl = *(const uint4*)&phiL[src];
        int row2 = tid >> 3, seg2 = tid & 7;
        rG = *(const uint4*)&gmat[((size_t)(b * NCI + row2)) * NN + m0 + seg2 * 8];
    };
    auto STORET = [&](unsigned short* dPh, unsigned short* dPl, unsigned short* dG) {
        int row = tid >> 4, seg = tid & 15;
        int dst = row * 128 + ((seg * 8) ^ ((row & 7) << 3));
        *(uint4*)&dPh[dst] = rPh;
        *(uint4*)&dPl[dst] = rPl;
        int row2 = tid >> 3, seg2 = tid & 7;
        *(uint4*)&dG[row2 * 64 + ((seg2 * 8) ^ ((row2 & 7) << 3))] = rG;
    };

    // ---------------- prologue: theta (log2e-scaled), C-range split across halves
    const int half = wave >> 3;                 // 0: c0 in {0,64}; 1: {128,192}
    const int wci8 = (wave & 7) * 16;           // ci rows covered by this wave
    f32x4 th[4];
#pragma unroll
    for (int j = 0; j < 4; j++)
#pragma unroll
        for (int e = 0; e < 4; e++) th[j][e] = 0.f;

    for (int s = 0; s < 2; s++) {
        {   // each 512-thread half stages its own c0 chunk of x (transpose+split)
            int set = tid >> 9;                 // == wave>>3
            int t = tid & 511;
            int cp = t >> 4, n4 = (t & 15) * 4;
            int myc0 = set * 128 + s * 64;
            unsigned short* dXh = set ? sXhB : sXhA;
            unsigned short* dXl = set ? sXlB : sXlA;
            const float* xp = x + ((size_t)(b * NC + myc0 + 2 * cp)) * NN + n0 + n4;
            float4 a = *(const float4*)xp;
            float4 c = *(const float4*)(xp + NN);
            float av[4] = { a.x, a.y, a.z, a.w };
            float cv4[4] = { c.x, c.y, c.z, c.w };
#pragma unroll
            for (int j = 0; j < 4; j++) {
                unsigned short ha = f2bf(av[j]), hc = f2bf(cv4[j]);
                unsigned short la = f2bf(av[j] - bf2f(ha)), lc = f2bf(cv4[j] - bf2f(hc));
                *(unsigned int*)&dXh[(n4 + j) * 72 + 2 * cp] =
                    (unsigned int)ha | ((unsigned int)hc << 16);
                *(unsigned int*)&dXl[(n4 + j) * 72 + 2 * cp] =
                    (unsigned int)la | ((unsigned int)lc << 16);
            }
        }
        __syncthreads();
        {
            int c0 = half * 128 + s * 64;
            const unsigned short* mXh = half ? sXhB : sXhA;
            const unsigned short* mXl = half ? sXlB : sXlA;
#pragma unroll
            for (int ks = 0; ks < 2; ks++) {
                size_t w = (size_t)(wci8 + col) * NC + c0 + ks * 32 + quad * 8;
                short8 ah = *(const short8*)&WtH[w];
                short8 al = *(const short8*)&WtL[w];
#pragma unroll
                for (int j = 0; j < 4; j++) {
                    short8 bh = *(const short8*)&mXh[(j * 16 + col) * 72 + ks * 32 + quad * 8];
                    short8 bl = *(const short8*)&mXl[(j * 16 + col) * 72 + ks * 32 + quad * 8];
                    th[j] = __builtin_amdgcn_mfma_f32_16x16x32_bf16(ah, bh, th[j], 0, 0, 0);
                    th[j] = __builtin_amdgcn_mfma_f32_16x16x32_bf16(ah, bl, th[j], 0, 0, 0);
                    th[j] = __builtin_amdgcn_mfma_f32_16x16x32_bf16(al, bh, th[j], 0, 0, 0);
                }
            }
        }
        __syncthreads();
    }
    // merge halves: half 0 writes f32 partials; half 1 adds, biases, splits hi/lo
    if (half == 0) {
#pragma unroll
        for (int j = 0; j < 4; j++) {
            int q = j * 16 + col;
            int ci = (wci8 + quad * 4) ^ ((q & 7) << 2);
            *(f32x4*)&sThF[q * 128 + ci] = th[j];
        }
    }
    __syncthreads();
    if (half == 1) {
#pragma unroll
        for (int j = 0; j < 4; j++) {
            int q = j * 16 + col;
            int cif = (wci8 + quad * 4) ^ ((q & 7) << 2);
            f32x4 o = *(const f32x4*)&sThF[q * 128 + cif];
            unsigned short h[4], l[4];
#pragma unroll
            for (int e = 0; e < 4; e++) {
                float v = o[e] + th[j][e] + bt[wci8 + quad * 4 + e] * LOG2E;
                h[e] = f2bf(v);
                l[e] = f2bf(v - bf2f(h[e]));
            }
            int cisw = (wci8 + quad * 4) ^ ((q & 7) << 3);
            uint2 hv, lv;
            hv.x = (unsigned int)h[0] | ((unsigned int)h[1] << 16);
            hv.y = (unsigned int)h[2] | ((unsigned int)h[3] << 16);
            lv.x = (unsigned int)l[0] | ((unsigned int)l[1] << 16);
            lv.y = (unsigned int)l[2] | ((unsigned int)l[3] << 16);
            *(uint2*)&sThH[q * 128 + cisw] = hv;
            *(uint2*)&sThL[q * 128 + cisw] = lv;
        }
    }
    __syncthreads();
    // theta fragments for this wave's 16-query group, held for the whole kernel
    short8 qh[4], ql[4];
    {
        int qrow = qg * 16 + col;
        int qsw = (qrow & 7) << 3;
#pragma unroll
        for (int ks = 0; ks < 4; ks++) {
            int off = (ks * 32 + quad * 8) ^ qsw;
            qh[ks] = *(const short8*)&sThH[qrow * 128 + off];
            ql[ks] = *(const short8*)&sThL[qrow * 128 + off];
        }
    }
    // prestage: tile 0 -> phi[0]/G[0]; tile 1 staged into registers
    LOADT(0);
    __syncthreads();                 // all waves finished reading sThH/sThL
    STORET(sPhiH0, sPhiL0, sGbase);  // tile 0 -> phi0, G slot 0
    LOADT(64);                       // tile 1 -> regs
    __syncthreads();                 // phi0/G0 visible

    // ---------------- main K-loop: 1 barrier/tile, 2-step unroll, static phi/P
    f32x4 oacc[2];
#pragma unroll
    for (int i = 0; i < 2; i++)
#pragma unroll
        for (int e = 0; e < 4; e++) oacc[i][e] = 0.f;
    float li[4] = { 0.f, 0.f, 0.f, 0.f };      // per-lane partial (this col's keys)

    auto step = [&](const unsigned short* cPhiH, const unsigned short* cPhiL,
                    unsigned short* nPhiH, unsigned short* nPhiL,
                    unsigned short* wG, const unsigned short* rGb,
                    unsigned short* wPall, const unsigned short* rPall,
                    int m_next, bool do_pv) {
        STORET(nPhiH, nPhiL, wG);
        LOADT(m_next);

        // QK(t): 16 queries (regs) x this wave's 16-key quarter
        f32x4 S;
#pragma unroll
        for (int e = 0; e < 4; e++) S[e] = 0.f;
        {
            int kcol = kh * 16 + col;
            int kswz = (kcol & 7) << 3;
#pragma unroll
            for (int ks = 0; ks < 4; ks++) {
                int off = (ks * 32 + quad * 8) ^ kswz;
                short8 ph = *(const short8*)&cPhiH[kcol * 128 + off];
                short8 pl = *(const short8*)&cPhiL[kcol * 128 + off];
                S = __builtin_amdgcn_mfma_f32_16x16x32_bf16(qh[ks], ph, S, 0, 0, 0);
                S = __builtin_amdgcn_mfma_f32_16x16x32_bf16(qh[ks], pl, S, 0, 0, 0);
                S = __builtin_amdgcn_mfma_f32_16x16x32_bf16(ql[ks], ph, S, 0, 0, 0);
            }
        }
        // PV(t-1): independent MFMAs fill the QK->exp2 dependency shadow
        if (do_pv) {
            short8 pf[2], af[2][2];
            int qrow = qg * 16 + col;
            int qsw = (qrow & 7) << 3;
#pragma unroll
            for (int ks = 0; ks < 2; ks++)
                pf[ks] = *(const short8*)&rPall[qrow * 64 + ((ks * 32 + quad * 8) ^ qsw)];
#pragma unroll
            for (int ct = 0; ct < 2; ct++) {
                int grow = kh * 32 + ct * 16 + col;
                int gsw = (grow & 7) << 3;
#pragma unroll
                for (int ks = 0; ks < 2; ks++)
                    af[ct][ks] = *(const short8*)&rGb[grow * 64 + ((ks * 32 + quad * 8) ^ gsw)];
            }
#pragma unroll
            for (int ct = 0; ct < 2; ct++)
#pragma unroll
                for (int ks = 0; ks < 2; ks++)
                    oacc[ct] = __builtin_amdgcn_mfma_f32_16x16x32_bf16(
                        af[ct][ks], pf[ks], oacc[ct], 0, 0, 0);
        }
        // softmax(t): per-lane li accumulation, P write swizzled
#pragma unroll
        for (int r = 0; r < 4; r++) {
            float p = exp2f(S[r]);
            li[r] += p;
            int q = qg * 16 + quad * 4 + r;
            wPall[q * 64 + ((kh * 16 + col) ^ ((q & 7) << 3))] = f2bf(p);
        }
        __syncthreads();             // single barrier per tile
    };

    // G slot offsets in shorts (slot k = k*8192). Step A = even t, B = odd t.
    int gwA = 8192, grA = 24576, gwB = 16384, grB = 0;
    for (int it = 0; it < 32; ++it) {
        int mA = it * 128 + 128; if (mA > 4032) mA = 4032;   // tile t+2 (clamped tail)
        int mB = it * 128 + 192; if (mB > 4032) mB = 4032;
        step(sPhiH0, sPhiL0, sPhiH1, sPhiL1, sGbase + gwA, sGbase + grA,
             sPall0, sPall1, mA, it != 0);
        step(sPhiH1, sPhiL1, sPhiH0, sPhiL0, sGbase + gwB, sGbase + grB,
             sPall1, sPall0, mB, true);
        gwA ^= 16384; grA ^= 16384; gwB ^= 16384; grB ^= 16384;
    }
    // final PV(63): P in pall[1], G in slot 63%4 = 3 (static)
    {
        short8 pf[2], af[2][2];
        int qrow = qg * 16 + col;
        int qsw = (qrow & 7) << 3;
#pragma unroll
        for (int ks = 0; ks < 2; ks++)
            pf[ks] = *(const short8*)&sPall1[qrow * 64 + ((ks * 32 + quad * 8) ^ qsw)];
#pragma unroll
        for (int ct = 0; ct < 2; ct++) {
            int grow = kh * 32 + ct * 16 + col;
            int gsw = (grow & 7) << 3;
#pragma unroll
            for (int ks = 0; ks < 2; ks++)
                af[ct][ks] = *(const short8*)&sGbase[24576 + grow * 64 + ((ks * 32 + quad * 8) ^ gsw)];
        }
#pragma unroll
        for (int ct = 0; ct < 2; ct++)
#pragma unroll
            for (int ks = 0; ks < 2; ks++)
                oacc[ct] = __builtin_amdgcn_mfma_f32_16x16x32_bf16(
                    af[ct][ks], pf[ks], oacc[ct], 0, 0, 0);
    }

    // ---------------- li: one wave-level reduce over the 16 cols, then merge kh
#pragma unroll
    for (int r = 0; r < 4; r++) {
        float rs = li[r];
#pragma unroll
        for (int off = 1; off < 16; off <<= 1) rs += __shfl_xor(rs, off);
        li[r] = rs;
    }
    if (col == 0) {
#pragma unroll
        for (int r = 0; r < 4; r++) sLi[wave * 16 + quad * 4 + r] = li[r];
    }
    __syncthreads();
    float inv = 1.0f / (sLi[(qg * 4 + 0) * 16 + col] + sLi[(qg * 4 + 1) * 16 + col] +
                        sLi[(qg * 4 + 2) * 16 + col] + sLi[(qg * 4 + 3) * 16 + col]);

    // O -> LDS (bf16, swizzled), overlays dead phi0
#pragma unroll
    for (int ct = 0; ct < 2; ct++) {
        int q = qg * 16 + col;
        int ci = kh * 32 + ct * 16 + quad * 4;
        int cisw = ci ^ ((q & 7) << 3);
        uint2 v;
        unsigned short p0 = f2bf(oacc[ct][0] * inv);
        unsigned short p1 = f2bf(oacc[ct][1] * inv);
        unsigned short p2 = f2bf(oacc[ct][2] * inv);
        unsigned short p3 = f2bf(oacc[ct][3] * inv);
        v.x = (unsigned int)p0 | ((unsigned int)p1 << 16);
        v.y = (unsigned int)p2 | ((unsigned int)p3 << 16);
        *(uint2*)&sO[q * 128 + cisw] = v;
    }
    __syncthreads();
    // out-proj: wave's 16-o tile + bias + residual; Wo A-frags straight from global
    f32x4 acc[4];
#pragma unroll
    for (int j = 0; j < 4; j++)
#pragma unroll
        for (int e = 0; e < 4; e++) acc[j][e] = 0.f;
#pragma unroll
    for (int ks = 0; ks < 4; ks++) {
        short8 af2 = *(const short8*)&WoH[(size_t)(wave * 16 + col) * NCI + ks * 32 + quad * 8];
#pragma unroll
        for (int j = 0; j < 4; j++) {
            int row = j * 16 + col;
            short8 bf = *(const short8*)&sO[row * 128 + ((ks * 32 + quad * 8) ^ ((row & 7) << 3))];
            acc[j] = __builtin_amdgcn_mfma_f32_16x16x32_bf16(af2, bf, acc[j], 0, 0, 0);
        }
    }
#pragma unroll
    for (int j = 0; j < 4; j++)
#pragma unroll
        for (int e = 0; e < 4; e++) {
            int o = wave * 16 + quad * 4 + e;
            size_t idx = ((size_t)(b * NC + o)) * NN + n0 + j * 16 + col;
            y[idx] = acc[j][e] + bo[o] + x[idx];
        }
}

// ---------------------------------------------------------------- launch
extern "C" void kernel_launch(void* const* d_in, const int* in_sizes, int n_in,
                              void* d_out, int out_size, void* d_ws, size_t ws_size,
                              hipStream_t stream) {
    float* y = (float*)d_out;

    bool sizes_ok = (n_in == 9) &&
        in_sizes[0] == NB * NC * NN && in_sizes[1] == NCI * NC && in_sizes[2] == NCI &&
        in_sizes[3] == NCI * NC && in_sizes[4] == NCI && in_sizes[5] == NCI * NC &&
        in_sizes[6] == NCI && in_sizes[7] == NC * NCI && in_sizes[8] == NC &&
        out_size == NB * NC * NN;
    if (!sizes_ok) {
        k_fill<<<(out_size + 255) / 256, 256, 0, stream>>>(y, 777.0f, out_size);
        return;
    }
    if (ws_size < (size_t)16 * 1024 * 1024) {
        k_fill<<<(out_size + 255) / 256, 256, 0, stream>>>(y, 555.0f, out_size);
        return;
    }

    const float* x  = (const float*)d_in[0];
    const float* tw = (const float*)d_in[1];
    const float* tb = (const float*)d_in[2];
    const float* pw = (const float*)d_in[3];
    const float* pb = (const float*)d_in[4];
    const float* gw = (const float*)d_in[5];
    const float* gb = (const float*)d_in[6];
    const float* ow = (const float*)d_in[7];
    const float* obias = (const float*)d_in[8];

    unsigned short* ws16 = (unsigned short*)d_ws;
    unsigned short* phiH = ws16;                 // [B][N][Ci] bf16 hi
    unsigned short* phiL = ws16 + 2097152;       // [B][N][Ci] bf16 lo
    unsigned short* g    = ws16 + 4194304;       // [B][Ci][N] bf16
    unsigned short* wbuf = ws16 + 6291456;       // WtH,WtL,WpH,WpL,WgH,WoH
    unsigned short* WtH = wbuf,           *WtL = wbuf + 32768;
    unsigned short* WpH = wbuf + 65536,   *WpL = wbuf + 98304;
    unsigned short* WgH = wbuf + 131072,  *WoH = wbuf + 163840;

    k_split<<<dim3(128, 4), 256, 0, stream>>>(tw, pw, gw, ow, wbuf);
    k_qkv2<<<dim3(128, NB), 256, 0, stream>>>(x, WpH, WpL, WgH, pb, gb, phiH, phiL, g);
    k_attn<<<dim3(256), 1024, 0, stream>>>(x, WtH, WtL, tb, phiH, phiL, g, WoH, obias, y);
}